// Round 2
// baseline (691.308 us; speedup 1.0000x reference)
//
#include <hip/hip_runtime.h>
#include <hip/hip_bf16.h>
#include <hip/hip_fp16.h>

// coif4 decomposition low-pass filter (L=24), fp32
constexpr int L = 24;
__device__ __constant__ float DEC_LO[L] = {
    -1.7849850030882614e-06f, -3.2596802368833675e-06f, 3.1229875865345646e-05f,
    6.233903446100713e-05f, -0.00025997455248771324f, -0.0005890207562443383f,
    0.0012665619292989445f, 0.003751436157278457f, -0.00565828668661072f,
    -0.015211731527946259f, 0.025082261844864097f, 0.03933442712333749f,
    -0.09622044203398798f, -0.06662747426342504f, 0.4343860564914685f,
    0.782238930920499f, 0.41530840703043026f, -0.05607731331675481f,
    -0.08126669968087875f, 0.026682300156053072f, 0.016068943964776348f,
    -0.0073461663276420935f, -0.0016294920126017326f, 0.0008923136685823146f
};

// g0[m] = DEC_LO[23-m] (reconstruction low), g1[m] = (-1)^m DEC_LO[m] (reconstruction high)
__device__ __forceinline__ float g0f(int m) { return DEC_LO[23 - m]; }
__device__ __forceinline__ float g1f(int m) { return (m & 1) ? -DEC_LO[m] : DEC_LO[m]; }

template <typename T> __device__ __forceinline__ void storev(T* p, float v);
template <> __device__ __forceinline__ void storev<float>(float* p, float v) { *p = v; }
template <> __device__ __forceinline__ void storev<__half>(__half* p, float v) { *p = __float2half_rn(v); }

// 1-D periodic inverse DWT along the H (row-index) axis.
// low/high: (C, n, W) logically (strides given); out: (C, 2n, W) of type OT.
// out[2q]   = sum_t g0[2t+1]*L[(q+5-t) mod n] + g1[2t+1]*H[(q+5-t) mod n]
// out[2q+1] = sum_t g0[2t]  *L[(q+6-t) mod n] + g1[2t]  *H[(q+6-t) mod n]
template <typename OT>
__global__ void colpass_kernel(const float* __restrict__ low, const float* __restrict__ high,
                               float sLow, float sHigh,
                               int lowCS, int highCS, int n, int W,
                               OT* __restrict__ out)
{
    int x = blockIdx.x * 64 + threadIdx.x;
    int q = blockIdx.y * blockDim.y + threadIdx.y;
    int c = blockIdx.z;
    int mask = n - 1;
    const float* lp = low + (size_t)c * lowCS + x;
    const float* hp = high + (size_t)c * highCS + x;
    float a0 = 0.f, a1 = 0.f;
#pragma unroll
    for (int s = 0; s <= 12; ++s) {
        int r = (q + 6 - s) & mask;
        float lv = sLow * lp[(size_t)r * W];
        float hv = sHigh * hp[(size_t)r * W];
        if (s >= 1)  a0 = fmaf(g0f(2 * s - 1), lv, fmaf(g1f(2 * s - 1), hv, a0));
        if (s <= 11) a1 = fmaf(g0f(2 * s), lv, fmaf(g1f(2 * s), hv, a1));
    }
    size_t ob = ((size_t)c * (2 * n) + 2 * q) * W + x;
    storev(&out[ob], a0);
    storev(&out[ob + W], a1);
}

// 1-D periodic inverse DWT along the W (last) axis, fp32 in/out.
// lo/hi: (C, N, n), N = 2n; out: (C, N, N).
__global__ void rowpass_kernel(const float* __restrict__ lo, const float* __restrict__ hi,
                               int n, float* __restrict__ out)
{
    int q = blockIdx.x * 64 + threadIdx.x;
    int y = blockIdx.y * blockDim.y + threadIdx.y;
    int c = blockIdx.z;
    int N = 2 * n, mask = n - 1;
    const float* lp = lo + ((size_t)c * N + y) * n;
    const float* hp = hi + ((size_t)c * N + y) * n;
    float a0 = 0.f, a1 = 0.f;
#pragma unroll
    for (int s = 0; s <= 12; ++s) {
        int r = (q + 6 - s) & mask;
        float lv = lp[r];
        float hv = hp[r];
        if (s >= 1)  a0 = fmaf(g0f(2 * s - 1), lv, fmaf(g1f(2 * s - 1), hv, a0));
        if (s <= 11) a1 = fmaf(g0f(2 * s), lv, fmaf(g1f(2 * s), hv, a1));
    }
    float2* op = (float2*)(out + ((size_t)c * N + y) * N + 2 * q);
    *op = make_float2(a0, a1);
}

// Level-3 rowpass fused with CHW->HWC transpose and fp16 output.
// lo/hi: (32, 1024, 512) fp16; out: HWC (1024, 1024, 32) fp16.
// Block: one y, 64 q (=128 x outputs), all 32 channels. 256 threads.
__global__ void rowpass_hwc_kernel(const __half* __restrict__ lo, const __half* __restrict__ hi,
                                   __half* __restrict__ out)
{
    const int n = 512, N = 1024, mask = 511;
    int y = blockIdx.y;
    int qbase = blockIdx.x * 64;
    int t = threadIdx.x;

    __shared__ __half lo_s[32][80];
    __shared__ __half hi_s[32][80];
    __shared__ __half po[32][130];   // [c][x-in-tile], padded

    // Stage input windows: r = (qbase - 8 + i) & 511, i in [0,80). r0 even -> half2-safe wrap.
    {
        int c = t >> 3;
        int j = t & 7;               // 8 threads/channel, 10 halves (5 half2) each
        const __half* lp = lo + ((size_t)c * N + y) * n;
        const __half* hp = hi + ((size_t)c * N + y) * n;
        int r0 = qbase - 8 + j * 10;
#pragma unroll
        for (int k = 0; k < 5; ++k) {
            int r = (r0 + 2 * k) & mask;
            *(__half2*)&lo_s[c][j * 10 + 2 * k] = *(const __half2*)&lp[r];
            *(__half2*)&hi_s[c][j * 10 + 2 * k] = *(const __half2*)&hp[r];
        }
    }
    __syncthreads();

    // Compute: each thread does one q for 8 channels.
    int dq = t & 63;
    int cg = t >> 6;
    int x0 = 2 * dq;
#pragma unroll
    for (int k = 0; k < 8; ++k) {
        int c = cg * 8 + k;
        float a0 = 0.f, a1 = 0.f;
#pragma unroll
        for (int s = 0; s <= 12; ++s) {
            int i = dq + 14 - s;     // in [2,77]
            float lv = __half2float(lo_s[c][i]);
            float hv = __half2float(hi_s[c][i]);
            if (s >= 1)  a0 = fmaf(g0f(2 * s - 1), lv, fmaf(g1f(2 * s - 1), hv, a0));
            if (s <= 11) a1 = fmaf(g0f(2 * s), lv, fmaf(g1f(2 * s), hv, a1));
        }
        *(__half2*)&po[c][x0] = __floats2half2_rn(a0, a1);
    }
    __syncthreads();

    // Coalesced HWC store: thread -> (pixel p = t>>1, channel half cc = (t&1)*16), 32 B each.
    {
        int p = t >> 1;
        int cc = (t & 1) * 16;
        unsigned int w[8];
#pragma unroll
        for (int k = 0; k < 8; ++k) {
            unsigned int l16 = __half_as_ushort(po[cc + 2 * k][p]);
            unsigned int h16 = __half_as_ushort(po[cc + 2 * k + 1][p]);
            w[k] = l16 | (h16 << 16);
        }
        size_t ob = ((size_t)y * 1024 + (size_t)qbase * 2 + p) * 32 + cc;
        *(uint4*)&out[ob]     = make_uint4(w[0], w[1], w[2], w[3]);
        *(uint4*)&out[ob + 8] = make_uint4(w[4], w[5], w[6], w[7]);
    }
}

// plane: HWC (1024,1024,32) fp16; pts: (npts,2) fp32; out: (npts,32) fp32.
// Thread handles one point x 2 channels (half2).
__global__ void sample_kernel(const float* __restrict__ pts, const __half2* __restrict__ plane,
                              float* __restrict__ out, int npts)
{
    int tid = blockIdx.x * 256 + threadIdx.x;
    int p = tid >> 4, c2 = tid & 15;
    float px = pts[2 * p + 0];
    float py = pts[2 * p + 1];
    float xf = fminf(fmaxf((px + 1.f) * 0.5f * 1023.f, 0.f), 1023.f);
    float yf = fminf(fmaxf((py + 1.f) * 0.5f * 1023.f, 0.f), 1023.f);
    int x0 = (int)xf, y0 = (int)yf;
    int x1 = min(x0 + 1, 1023), y1 = min(y0 + 1, 1023);
    float wx = xf - (float)x0, wy = yf - (float)y0;
    size_t r0 = (size_t)y0 * 1024, r1 = (size_t)y1 * 1024;
    float2 f00 = __half22float2(plane[(r0 + x0) * 16 + c2]);
    float2 f01 = __half22float2(plane[(r0 + x1) * 16 + c2]);
    float2 f10 = __half22float2(plane[(r1 + x0) * 16 + c2]);
    float2 f11 = __half22float2(plane[(r1 + x1) * 16 + c2]);
    float2 r;
    r.x = (f00.x * (1.f - wx) + f01.x * wx) * (1.f - wy) + (f10.x * (1.f - wx) + f11.x * wx) * wy;
    r.y = (f00.y * (1.f - wx) + f01.y * wx) * (1.f - wy) + (f10.y * (1.f - wx) + f11.y * wx) * wy;
    *(float2*)&out[(size_t)p * 32 + 2 * c2] = r;
}

extern "C" void kernel_launch(void* const* d_in, const int* in_sizes, int n_in,
                              void* d_out, int out_size, void* d_ws, size_t ws_size,
                              hipStream_t stream)
{
    const float* pts = (const float*)d_in[0];
    const float* yl  = (const float*)d_in[1];
    const float* yh0 = (const float*)d_in[2]; // (32,3,512,512), scale 0.2, level 3
    const float* yh1 = (const float*)d_in[3]; // (32,3,256,256), scale 0.4, level 2
    const float* yh2 = (const float*)d_in[4]; // (32,3,128,128), scale 0.6, level 1
    const int C = 32;
    const int npts = in_sizes[0] / 2;

    // Workspace layout (bytes), total 167.8 MB:
    //   [0,          33554432)  llbuf  fp32 (up to C x 512 x 512)
    //   [33554432,   67108864)  tmpA   fp32 (L1/L2) / fp16 (L3, C x 1024 x 512)
    //   [67108864,  100663296)  tmpB   same
    //   [100663296, 167772160)  plane  fp16 HWC (1024,1024,32)
    char* ws = (char*)d_ws;
    float*  llbuf = (float*)ws;
    float*  tmpA  = (float*)(ws + 33554432);
    float*  tmpB  = (float*)(ws + 67108864);
    __half* tmpAh = (__half*)(ws + 33554432);
    __half* tmpBh = (__half*)(ws + 67108864);
    __half* plane = (__half*)(ws + 100663296);

    dim3 cb(64, 4, 1);

    // ---- Level 1: n=128 -> 256. details yh2 * 0.6, ll = yl * 1.0
    {
        int n = 128, nn = n * n;
        dim3 cg(n / 64, n / 4, C);
        colpass_kernel<float><<<cg, cb, 0, stream>>>(yl, yh2 + 0 * nn, 1.0f, 0.6f, nn, 3 * nn, n, n, tmpA);
        colpass_kernel<float><<<cg, cb, 0, stream>>>(yh2 + 1 * nn, yh2 + 2 * nn, 0.6f, 0.6f, 3 * nn, 3 * nn, n, n, tmpB);
        dim3 rg(n / 64, (2 * n) / 4, C);
        rowpass_kernel<<<rg, cb, 0, stream>>>(tmpA, tmpB, n, llbuf);
    }
    // ---- Level 2: n=256 -> 512. details yh1 * 0.4
    {
        int n = 256, nn = n * n;
        dim3 cg(n / 64, n / 4, C);
        colpass_kernel<float><<<cg, cb, 0, stream>>>(llbuf, yh1 + 0 * nn, 1.0f, 0.4f, nn, 3 * nn, n, n, tmpA);
        colpass_kernel<float><<<cg, cb, 0, stream>>>(yh1 + 1 * nn, yh1 + 2 * nn, 0.4f, 0.4f, 3 * nn, 3 * nn, n, n, tmpB);
        dim3 rg(n / 64, (2 * n) / 4, C);
        rowpass_kernel<<<rg, cb, 0, stream>>>(tmpA, tmpB, n, llbuf);
    }
    // ---- Level 3: n=512 -> 1024. details yh0 * 0.2; fp16 tmps
    {
        int n = 512, nn = n * n;
        dim3 cg(n / 64, n / 4, C);
        colpass_kernel<__half><<<cg, cb, 0, stream>>>(llbuf, yh0 + 0 * nn, 1.0f, 0.2f, nn, 3 * nn, n, n, tmpAh);
        colpass_kernel<__half><<<cg, cb, 0, stream>>>(yh0 + 1 * nn, yh0 + 2 * nn, 0.2f, 0.2f, 3 * nn, 3 * nn, n, n, tmpBh);
        // fused rowpass + transpose -> HWC fp16
        dim3 rg(8, 1024);
        rowpass_hwc_kernel<<<rg, 256, 0, stream>>>(tmpAh, tmpBh, plane);
    }
    // ---- Bilinear sampling from fp16 HWC plane
    sample_kernel<<<(npts * 16) / 256, 256, 0, stream>>>(pts, (const __half2*)plane, (float*)d_out, npts);
}

// Round 3
// 340.531 us; speedup vs baseline: 2.0301x; 2.0301x over previous
//
#include <hip/hip_runtime.h>
#include <hip/hip_bf16.h>
#include <hip/hip_fp16.h>

// coif4 decomposition low-pass filter (L=24), fp32
constexpr int L = 24;
__device__ __constant__ float DEC_LO[L] = {
    -1.7849850030882614e-06f, -3.2596802368833675e-06f, 3.1229875865345646e-05f,
    6.233903446100713e-05f, -0.00025997455248771324f, -0.0005890207562443383f,
    0.0012665619292989445f, 0.003751436157278457f, -0.00565828668661072f,
    -0.015211731527946259f, 0.025082261844864097f, 0.03933442712333749f,
    -0.09622044203398798f, -0.06662747426342504f, 0.4343860564914685f,
    0.782238930920499f, 0.41530840703043026f, -0.05607731331675481f,
    -0.08126669968087875f, 0.026682300156053072f, 0.016068943964776348f,
    -0.0073461663276420935f, -0.0016294920126017326f, 0.0008923136685823146f
};

// g0[m] = DEC_LO[23-m] (reconstruction low), g1[m] = (-1)^m DEC_LO[m] (reconstruction high)
__device__ __forceinline__ float g0f(int m) { return DEC_LO[23 - m]; }
__device__ __forceinline__ float g1f(int m) { return (m & 1) ? -DEC_LO[m] : DEC_LO[m]; }

template <typename T> __device__ __forceinline__ void storev(T* p, float v);
template <> __device__ __forceinline__ void storev<float>(float* p, float v) { *p = v; }
template <> __device__ __forceinline__ void storev<__half>(__half* p, float v) { *p = __float2half_rn(v); }

// 1-D periodic inverse DWT along the H (row-index) axis.
// low/high: (C, n, W) logically (strides given); out: (C, 2n, W) of type OT.
// out[2q]   = sum_t g0[2t+1]*L[(q+5-t) mod n] + g1[2t+1]*H[(q+5-t) mod n]
// out[2q+1] = sum_t g0[2t]  *L[(q+6-t) mod n] + g1[2t]  *H[(q+6-t) mod n]
template <typename OT>
__global__ void colpass_kernel(const float* __restrict__ low, const float* __restrict__ high,
                               float sLow, float sHigh,
                               int lowCS, int highCS, int n, int W,
                               OT* __restrict__ out)
{
    int x = blockIdx.x * 64 + threadIdx.x;
    int q = blockIdx.y * blockDim.y + threadIdx.y;
    int c = blockIdx.z;
    int mask = n - 1;
    const float* lp = low + (size_t)c * lowCS + x;
    const float* hp = high + (size_t)c * highCS + x;
    float a0 = 0.f, a1 = 0.f;
#pragma unroll
    for (int s = 0; s <= 12; ++s) {
        int r = (q + 6 - s) & mask;
        float lv = sLow * lp[(size_t)r * W];
        float hv = sHigh * hp[(size_t)r * W];
        if (s >= 1)  a0 = fmaf(g0f(2 * s - 1), lv, fmaf(g1f(2 * s - 1), hv, a0));
        if (s <= 11) a1 = fmaf(g0f(2 * s), lv, fmaf(g1f(2 * s), hv, a1));
    }
    size_t ob = ((size_t)c * (2 * n) + 2 * q) * W + x;
    storev(&out[ob], a0);
    storev(&out[ob + W], a1);
}

// 1-D periodic inverse DWT along the W (last) axis, fp32 in/out.
// lo/hi: (C, N, n), N = 2n; out: (C, N, N).
__global__ void rowpass_kernel(const float* __restrict__ lo, const float* __restrict__ hi,
                               int n, float* __restrict__ out)
{
    int q = blockIdx.x * 64 + threadIdx.x;
    int y = blockIdx.y * blockDim.y + threadIdx.y;
    int c = blockIdx.z;
    int N = 2 * n, mask = n - 1;
    const float* lp = lo + ((size_t)c * N + y) * n;
    const float* hp = hi + ((size_t)c * N + y) * n;
    float a0 = 0.f, a1 = 0.f;
#pragma unroll
    for (int s = 0; s <= 12; ++s) {
        int r = (q + 6 - s) & mask;
        float lv = lp[r];
        float hv = hp[r];
        if (s >= 1)  a0 = fmaf(g0f(2 * s - 1), lv, fmaf(g1f(2 * s - 1), hv, a0));
        if (s <= 11) a1 = fmaf(g0f(2 * s), lv, fmaf(g1f(2 * s), hv, a1));
    }
    float2* op = (float2*)(out + ((size_t)c * N + y) * N + 2 * q);
    *op = make_float2(a0, a1);
}

// Level-3 rowpass, fp16 in / fp16 out, CHW. Register-only streaming pattern
// (identical structure to rowpass_kernel, which ran near HBM BW).
__global__ void rowpass16_kernel(const __half* __restrict__ lo, const __half* __restrict__ hi,
                                 __half* __restrict__ out)
{
    const int n = 512, N = 1024, mask = 511;
    int q = blockIdx.x * 64 + threadIdx.x;
    int y = blockIdx.y * blockDim.y + threadIdx.y;
    int c = blockIdx.z;
    const __half* lp = lo + ((size_t)c * N + y) * n;
    const __half* hp = hi + ((size_t)c * N + y) * n;
    float a0 = 0.f, a1 = 0.f;
#pragma unroll
    for (int s = 0; s <= 12; ++s) {
        int r = (q + 6 - s) & mask;
        float lv = __half2float(lp[r]);
        float hv = __half2float(hp[r]);
        if (s >= 1)  a0 = fmaf(g0f(2 * s - 1), lv, fmaf(g1f(2 * s - 1), hv, a0));
        if (s <= 11) a1 = fmaf(g0f(2 * s), lv, fmaf(g1f(2 * s), hv, a1));
    }
    __half2* op = (__half2*)(out + ((size_t)c * N + y) * N + 2 * q);
    *op = __floats2half2_rn(a0, a1);
}

// fp16 CHW (32, 1048576) -> HWC (1048576, 32). LDS tiled, 128 pixels/block,
// ushort2 (4 B) granularity both sides, padded tile for conflict-free access.
__global__ void chw2hwc16_kernel(const ushort2* __restrict__ src, ushort2* __restrict__ dst)
{
    __shared__ ushort2 tile[32][67];
    int base = blockIdx.x * 128;          // pixel base
    int t = threadIdx.x;
    // Load: 32 ch x 64 ushort2; wave reads 256 B contiguous per channel.
#pragma unroll
    for (int k = 0; k < 8; ++k) {
        int idx = k * 256 + t;
        int c = idx >> 6, xh = idx & 63;  // xh = pixel-pair index
        tile[c][xh] = src[(size_t)c * 524288 + (base >> 1) + xh];
    }
    __syncthreads();
    // Store: per pixel, 32 channels = 32 ushort2 contiguous.
#pragma unroll
    for (int k = 0; k < 8; ++k) {
        int idx = k * 256 + t;
        int pix = idx >> 4, cp = idx & 15;            // cp = channel pair
        ushort u0 = ((const ushort*)&tile[2 * cp][0])[pix];
        ushort u1 = ((const ushort*)&tile[2 * cp + 1][0])[pix];
        dst[((size_t)(base + pix) * 32 >> 1) + cp] = make_ushort2(u0, u1);
    }
}

// plane: HWC (1024,1024,32) fp16; pts: (npts,2) fp32; out: (npts,32) fp32.
// Thread handles one point x 2 channels (half2).
__global__ void sample_kernel(const float* __restrict__ pts, const __half2* __restrict__ plane,
                              float* __restrict__ out, int npts)
{
    int tid = blockIdx.x * 256 + threadIdx.x;
    int p = tid >> 4, c2 = tid & 15;
    float px = pts[2 * p + 0];
    float py = pts[2 * p + 1];
    float xf = fminf(fmaxf((px + 1.f) * 0.5f * 1023.f, 0.f), 1023.f);
    float yf = fminf(fmaxf((py + 1.f) * 0.5f * 1023.f, 0.f), 1023.f);
    int x0 = (int)xf, y0 = (int)yf;
    int x1 = min(x0 + 1, 1023), y1 = min(y0 + 1, 1023);
    float wx = xf - (float)x0, wy = yf - (float)y0;
    size_t r0 = (size_t)y0 * 1024, r1 = (size_t)y1 * 1024;
    float2 f00 = __half22float2(plane[(r0 + x0) * 16 + c2]);
    float2 f01 = __half22float2(plane[(r0 + x1) * 16 + c2]);
    float2 f10 = __half22float2(plane[(r1 + x0) * 16 + c2]);
    float2 f11 = __half22float2(plane[(r1 + x1) * 16 + c2]);
    float2 r;
    r.x = (f00.x * (1.f - wx) + f01.x * wx) * (1.f - wy) + (f10.x * (1.f - wx) + f11.x * wx) * wy;
    r.y = (f00.y * (1.f - wx) + f01.y * wx) * (1.f - wy) + (f10.y * (1.f - wx) + f11.y * wx) * wy;
    *(float2*)&out[(size_t)p * 32 + 2 * c2] = r;
}

extern "C" void kernel_launch(void* const* d_in, const int* in_sizes, int n_in,
                              void* d_out, int out_size, void* d_ws, size_t ws_size,
                              hipStream_t stream)
{
    const float* pts = (const float*)d_in[0];
    const float* yl  = (const float*)d_in[1];
    const float* yh0 = (const float*)d_in[2]; // (32,3,512,512), scale 0.2, level 3
    const float* yh1 = (const float*)d_in[3]; // (32,3,256,256), scale 0.4, level 2
    const float* yh2 = (const float*)d_in[4]; // (32,3,128,128), scale 0.6, level 1
    const int C = 32;
    const int npts = in_sizes[0] / 2;

    // Workspace layout (bytes), total 235 MB:
    //   [0,          33554432)  llbuf    fp32 (up to C x 512 x 512)
    //   [33554432,   67108864)  tmpA     fp32 (L1/L2) / fp16 (L3: C x 1024 x 512)
    //   [67108864,  100663296)  tmpB     same
    //   [100663296, 167772160)  planeCHW fp16 (C,1024,1024)
    //   [167772160, 234881024)  planeHWC fp16 (1024,1024,C)
    char* ws = (char*)d_ws;
    float*  llbuf    = (float*)ws;
    float*  tmpA     = (float*)(ws + 33554432);
    float*  tmpB     = (float*)(ws + 67108864);
    __half* tmpAh    = (__half*)(ws + 33554432);
    __half* tmpBh    = (__half*)(ws + 67108864);
    __half* planeCHW = (__half*)(ws + 100663296);
    __half* planeHWC = (__half*)(ws + 167772160);

    dim3 cb(64, 4, 1);

    // ---- Level 1: n=128 -> 256. details yh2 * 0.6, ll = yl * 1.0
    {
        int n = 128, nn = n * n;
        dim3 cg(n / 64, n / 4, C);
        colpass_kernel<float><<<cg, cb, 0, stream>>>(yl, yh2 + 0 * nn, 1.0f, 0.6f, nn, 3 * nn, n, n, tmpA);
        colpass_kernel<float><<<cg, cb, 0, stream>>>(yh2 + 1 * nn, yh2 + 2 * nn, 0.6f, 0.6f, 3 * nn, 3 * nn, n, n, tmpB);
        dim3 rg(n / 64, (2 * n) / 4, C);
        rowpass_kernel<<<rg, cb, 0, stream>>>(tmpA, tmpB, n, llbuf);
    }
    // ---- Level 2: n=256 -> 512. details yh1 * 0.4
    {
        int n = 256, nn = n * n;
        dim3 cg(n / 64, n / 4, C);
        colpass_kernel<float><<<cg, cb, 0, stream>>>(llbuf, yh1 + 0 * nn, 1.0f, 0.4f, nn, 3 * nn, n, n, tmpA);
        colpass_kernel<float><<<cg, cb, 0, stream>>>(yh1 + 1 * nn, yh1 + 2 * nn, 0.4f, 0.4f, 3 * nn, 3 * nn, n, n, tmpB);
        dim3 rg(n / 64, (2 * n) / 4, C);
        rowpass_kernel<<<rg, cb, 0, stream>>>(tmpA, tmpB, n, llbuf);
    }
    // ---- Level 3: n=512 -> 1024. details yh0 * 0.2; fp16 tmps + fp16 plane
    {
        int n = 512, nn = n * n;
        dim3 cg(n / 64, n / 4, C);
        colpass_kernel<__half><<<cg, cb, 0, stream>>>(llbuf, yh0 + 0 * nn, 1.0f, 0.2f, nn, 3 * nn, n, n, tmpAh);
        colpass_kernel<__half><<<cg, cb, 0, stream>>>(yh0 + 1 * nn, yh0 + 2 * nn, 0.2f, 0.2f, 3 * nn, 3 * nn, n, n, tmpBh);
        dim3 rg(n / 64, (2 * n) / 4, C);
        rowpass16_kernel<<<rg, cb, 0, stream>>>(tmpAh, tmpBh, planeCHW);
    }
    // ---- fp16 CHW -> HWC transpose (coalesced both sides, LDS tiled)
    chw2hwc16_kernel<<<8192, 256, 0, stream>>>((const ushort2*)planeCHW, (ushort2*)planeHWC);
    // ---- Bilinear sampling from fp16 HWC plane
    sample_kernel<<<(npts * 16) / 256, 256, 0, stream>>>(pts, (const __half2*)planeHWC, (float*)d_out, npts);
}

// Round 4
// 285.117 us; speedup vs baseline: 2.4247x; 1.1944x over previous
//
#include <hip/hip_runtime.h>
#include <hip/hip_bf16.h>
#include <hip/hip_fp16.h>

// coif4 decomposition low-pass filter (L=24), fp32
constexpr int L = 24;
__device__ __constant__ float DEC_LO[L] = {
    -1.7849850030882614e-06f, -3.2596802368833675e-06f, 3.1229875865345646e-05f,
    6.233903446100713e-05f, -0.00025997455248771324f, -0.0005890207562443383f,
    0.0012665619292989445f, 0.003751436157278457f, -0.00565828668661072f,
    -0.015211731527946259f, 0.025082261844864097f, 0.03933442712333749f,
    -0.09622044203398798f, -0.06662747426342504f, 0.4343860564914685f,
    0.782238930920499f, 0.41530840703043026f, -0.05607731331675481f,
    -0.08126669968087875f, 0.026682300156053072f, 0.016068943964776348f,
    -0.0073461663276420935f, -0.0016294920126017326f, 0.0008923136685823146f
};

// g0[m] = DEC_LO[23-m] (reconstruction low), g1[m] = (-1)^m DEC_LO[m] (reconstruction high)
__device__ __forceinline__ float g0f(int m) { return DEC_LO[23 - m]; }
__device__ __forceinline__ float g1f(int m) { return (m & 1) ? -DEC_LO[m] : DEC_LO[m]; }

// ---------------- L1/L2 kernels (small, unchanged from R3) ----------------

__global__ void colpass_kernel(const float* __restrict__ low, const float* __restrict__ high,
                               float sLow, float sHigh,
                               int lowCS, int highCS, int n, int W,
                               float* __restrict__ out)
{
    int x = blockIdx.x * 64 + threadIdx.x;
    int q = blockIdx.y * blockDim.y + threadIdx.y;
    int c = blockIdx.z;
    int mask = n - 1;
    const float* lp = low + (size_t)c * lowCS + x;
    const float* hp = high + (size_t)c * highCS + x;
    float a0 = 0.f, a1 = 0.f;
#pragma unroll
    for (int s = 0; s <= 12; ++s) {
        int r = (q + 6 - s) & mask;
        float lv = sLow * lp[(size_t)r * W];
        float hv = sHigh * hp[(size_t)r * W];
        if (s >= 1)  a0 = fmaf(g0f(2 * s - 1), lv, fmaf(g1f(2 * s - 1), hv, a0));
        if (s <= 11) a1 = fmaf(g0f(2 * s), lv, fmaf(g1f(2 * s), hv, a1));
    }
    size_t ob = ((size_t)c * (2 * n) + 2 * q) * W + x;
    out[ob] = a0;
    out[ob + W] = a1;
}

__global__ void rowpass_kernel(const float* __restrict__ lo, const float* __restrict__ hi,
                               int n, float* __restrict__ out)
{
    int q = blockIdx.x * 64 + threadIdx.x;
    int y = blockIdx.y * blockDim.y + threadIdx.y;
    int c = blockIdx.z;
    int N = 2 * n, mask = n - 1;
    const float* lp = lo + ((size_t)c * N + y) * n;
    const float* hp = hi + ((size_t)c * N + y) * n;
    float a0 = 0.f, a1 = 0.f;
#pragma unroll
    for (int s = 0; s <= 12; ++s) {
        int r = (q + 6 - s) & mask;
        float lv = lp[r];
        float hv = hp[r];
        if (s >= 1)  a0 = fmaf(g0f(2 * s - 1), lv, fmaf(g1f(2 * s - 1), hv, a0));
        if (s <= 11) a1 = fmaf(g0f(2 * s), lv, fmaf(g1f(2 * s), hv, a1));
    }
    float2* op = (float2*)(out + ((size_t)c * N + y) * N + 2 * q);
    *op = make_float2(a0, a1);
}

// ---------------- Level-3 colpass: float4-vectorized over x, fp16 out ----------------
// lo/hi: (32, 512, 512) fp32 (channel strides in float4 units); out: (32, 1024, 512) fp16.
__global__ void colpass4h_kernel(const float4* __restrict__ lo, const float4* __restrict__ hi,
                                 float sLow, float sHigh, int loCS4, int hiCS4,
                                 __half* __restrict__ out)
{
    const int mask = 511, W4 = 128;
    int x = blockIdx.x * 64 + threadIdx.x;   // float4 index, [0,128)
    int q = blockIdx.y * 4 + threadIdx.y;    // [0,512)
    int c = blockIdx.z;
    const float4* lp = lo + (size_t)c * loCS4 + x;
    const float4* hp = hi + (size_t)c * hiCS4 + x;
    float4 a0 = make_float4(0.f, 0.f, 0.f, 0.f);
    float4 a1 = make_float4(0.f, 0.f, 0.f, 0.f);
#pragma unroll
    for (int s = 0; s <= 12; ++s) {
        int r = (q + 6 - s) & mask;
        float4 lv = lp[(size_t)r * W4];
        float4 hv = hp[(size_t)r * W4];
        if (s >= 1) {
            float gl = g0f(2 * s - 1) * sLow, gh = g1f(2 * s - 1) * sHigh;
            a0.x = fmaf(gl, lv.x, fmaf(gh, hv.x, a0.x));
            a0.y = fmaf(gl, lv.y, fmaf(gh, hv.y, a0.y));
            a0.z = fmaf(gl, lv.z, fmaf(gh, hv.z, a0.z));
            a0.w = fmaf(gl, lv.w, fmaf(gh, hv.w, a0.w));
        }
        if (s <= 11) {
            float gl = g0f(2 * s) * sLow, gh = g1f(2 * s) * sHigh;
            a1.x = fmaf(gl, lv.x, fmaf(gh, hv.x, a1.x));
            a1.y = fmaf(gl, lv.y, fmaf(gh, hv.y, a1.y));
            a1.z = fmaf(gl, lv.z, fmaf(gh, hv.z, a1.z));
            a1.w = fmaf(gl, lv.w, fmaf(gh, hv.w, a1.w));
        }
    }
    // rows 2q and 2q+1, 4 halves each (8 B stores)
    size_t ob = ((size_t)c * 1024 + 2 * q) * 512 + 4 * x;
    __half2 p0 = __floats2half2_rn(a0.x, a0.y), p1 = __floats2half2_rn(a0.z, a0.w);
    __half2 p2 = __floats2half2_rn(a1.x, a1.y), p3 = __floats2half2_rn(a1.z, a1.w);
    uint2 w0 = make_uint2(*(unsigned int*)&p0, *(unsigned int*)&p1);
    uint2 w1 = make_uint2(*(unsigned int*)&p2, *(unsigned int*)&p3);
    *(uint2*)&out[ob] = w0;
    *(uint2*)&out[ob + 512] = w1;
}

// ---------------- Level-3 rowpass fused with HWC output ----------------
// lo/hi: (32, 1024, 512) fp16; out: HWC (1024, 1024, 32) fp16.
// Block = 256 threads: 32 channel-groups x 8 q-threads; covers one y, 64 q (128 px).
// Compute is register-only from 16B vector loads; LDS used once for output transpose.
__global__ void rowpass16_hwc_kernel(const __half* __restrict__ lo, const __half* __restrict__ hi,
                                     __half* __restrict__ out)
{
    const int n = 512, N = 1024, mask = 511;
    int y = blockIdx.y;
    int qb = blockIdx.x * 64;
    int t = threadIdx.x;
    int c = t >> 3;          // channel
    int tq = t & 7;          // q-subtile
    int q0 = qb + tq * 8;

    const __half* lp = lo + ((size_t)c * N + y) * n;
    const __half* hp = hi + ((size_t)c * N + y) * n;

    // Window [q0-8, q0+16) as 3 aligned 16B chunks per operand.
    float wlo[24], whi[24];
#pragma unroll
    for (int k = 0; k < 3; ++k) {
        int s0 = (q0 - 8 + 8 * k) & mask;     // multiple of 8 -> 16B aligned, no intra-chunk wrap
        float4 vl = *(const float4*)(lp + s0);
        float4 vh = *(const float4*)(hp + s0);
        const __half2* hl = (const __half2*)&vl;
        const __half2* hh = (const __half2*)&vh;
#pragma unroll
        for (int j = 0; j < 4; ++j) {
            float2 fl = __half22float2(hl[j]);
            float2 fh = __half22float2(hh[j]);
            wlo[k * 8 + 2 * j]     = fl.x;
            wlo[k * 8 + 2 * j + 1] = fl.y;
            whi[k * 8 + 2 * j]     = fh.x;
            whi[k * 8 + 2 * j + 1] = fh.y;
        }
    }

    __shared__ __half tile[128][34];   // [pixel-in-block][channel], padded

#pragma unroll
    for (int j = 0; j < 8; ++j) {
        float a0 = 0.f, a1 = 0.f;
#pragma unroll
        for (int s = 0; s <= 12; ++s) {
            int li = j + 14 - s;       // window index for (q0+j+6-s)
            float lv = wlo[li];
            float hv = whi[li];
            if (s >= 1)  a0 = fmaf(g0f(2 * s - 1), lv, fmaf(g1f(2 * s - 1), hv, a0));
            if (s <= 11) a1 = fmaf(g0f(2 * s), lv, fmaf(g1f(2 * s), hv, a1));
        }
        int pl = 16 * tq + 2 * j;
        tile[pl][c]     = __float2half_rn(a0);
        tile[pl + 1][c] = __float2half_rn(a1);
    }
    __syncthreads();

    // Coalesced HWC store: thread -> pixel p = t>>1, channels c0 = (t&1)*16 .. +15 (32 B).
    int p = t >> 1;
    int c0 = (t & 1) * 16;
    unsigned int w[8];
#pragma unroll
    for (int k = 0; k < 8; ++k) {
        unsigned int l16 = __half_as_ushort(tile[p][c0 + 2 * k]);
        unsigned int h16 = __half_as_ushort(tile[p][c0 + 2 * k + 1]);
        w[k] = l16 | (h16 << 16);
    }
    size_t ob = ((size_t)y * 1024 + 2 * qb + p) * 32 + c0;
    *(uint4*)&out[ob]     = make_uint4(w[0], w[1], w[2], w[3]);
    *(uint4*)&out[ob + 8] = make_uint4(w[4], w[5], w[6], w[7]);
}

// ---------------- Sampler: 4 threads/point, 16B corner loads ----------------
struct alignas(16) HV { __half2 h[4]; };

__global__ void sample_kernel(const float* __restrict__ pts, const __half* __restrict__ plane,
                              float* __restrict__ out, int npts)
{
    int tid = blockIdx.x * 256 + threadIdx.x;
    int p = tid >> 2, cg = (tid & 3) * 8;
    if (p >= npts) return;
    float px = pts[2 * p + 0];
    float py = pts[2 * p + 1];
    float xf = fminf(fmaxf((px + 1.f) * 0.5f * 1023.f, 0.f), 1023.f);
    float yf = fminf(fmaxf((py + 1.f) * 0.5f * 1023.f, 0.f), 1023.f);
    int x0 = (int)xf, y0 = (int)yf;
    int x1 = min(x0 + 1, 1023), y1 = min(y0 + 1, 1023);
    float wx = xf - (float)x0, wy = yf - (float)y0;
    size_t r0 = (size_t)y0 * 1024, r1 = (size_t)y1 * 1024;
    HV v00 = *(const HV*)(plane + (r0 + x0) * 32 + cg);
    HV v01 = *(const HV*)(plane + (r0 + x1) * 32 + cg);
    HV v10 = *(const HV*)(plane + (r1 + x0) * 32 + cg);
    HV v11 = *(const HV*)(plane + (r1 + x1) * 32 + cg);
    float o[8];
#pragma unroll
    for (int k = 0; k < 4; ++k) {
        float2 f00 = __half22float2(v00.h[k]);
        float2 f01 = __half22float2(v01.h[k]);
        float2 f10 = __half22float2(v10.h[k]);
        float2 f11 = __half22float2(v11.h[k]);
        o[2 * k]     = (f00.x * (1.f - wx) + f01.x * wx) * (1.f - wy)
                     + (f10.x * (1.f - wx) + f11.x * wx) * wy;
        o[2 * k + 1] = (f00.y * (1.f - wx) + f01.y * wx) * (1.f - wy)
                     + (f10.y * (1.f - wx) + f11.y * wx) * wy;
    }
    float* ob = out + (size_t)p * 32 + cg;
    *(float4*)ob       = make_float4(o[0], o[1], o[2], o[3]);
    *(float4*)(ob + 4) = make_float4(o[4], o[5], o[6], o[7]);
}

extern "C" void kernel_launch(void* const* d_in, const int* in_sizes, int n_in,
                              void* d_out, int out_size, void* d_ws, size_t ws_size,
                              hipStream_t stream)
{
    const float* pts = (const float*)d_in[0];
    const float* yl  = (const float*)d_in[1];
    const float* yh0 = (const float*)d_in[2]; // (32,3,512,512), scale 0.2, level 3
    const float* yh1 = (const float*)d_in[3]; // (32,3,256,256), scale 0.4, level 2
    const float* yh2 = (const float*)d_in[4]; // (32,3,128,128), scale 0.6, level 1
    const int C = 32;
    const int npts = in_sizes[0] / 2;

    // Workspace layout (bytes), total 167.8 MB:
    //   [0,          33554432)  llbuf    fp32 (up to C x 512 x 512)
    //   [33554432,   67108864)  tmpA     fp32 (L1/L2) / fp16 (L3: C x 1024 x 512)
    //   [67108864,  100663296)  tmpB     same
    //   [100663296, 167772160)  planeHWC fp16 (1024,1024,C)
    char* ws = (char*)d_ws;
    float*  llbuf    = (float*)ws;
    float*  tmpA     = (float*)(ws + 33554432);
    float*  tmpB     = (float*)(ws + 67108864);
    __half* tmpAh    = (__half*)(ws + 33554432);
    __half* tmpBh    = (__half*)(ws + 67108864);
    __half* planeHWC = (__half*)(ws + 100663296);

    dim3 cb(64, 4, 1);

    // ---- Level 1: n=128 -> 256. details yh2 * 0.6, ll = yl * 1.0
    {
        int n = 128, nn = n * n;
        dim3 cg(n / 64, n / 4, C);
        colpass_kernel<<<cg, cb, 0, stream>>>(yl, yh2 + 0 * nn, 1.0f, 0.6f, nn, 3 * nn, n, n, tmpA);
        colpass_kernel<<<cg, cb, 0, stream>>>(yh2 + 1 * nn, yh2 + 2 * nn, 0.6f, 0.6f, 3 * nn, 3 * nn, n, n, tmpB);
        dim3 rg(n / 64, (2 * n) / 4, C);
        rowpass_kernel<<<rg, cb, 0, stream>>>(tmpA, tmpB, n, llbuf);
    }
    // ---- Level 2: n=256 -> 512. details yh1 * 0.4
    {
        int n = 256, nn = n * n;
        dim3 cg(n / 64, n / 4, C);
        colpass_kernel<<<cg, cb, 0, stream>>>(llbuf, yh1 + 0 * nn, 1.0f, 0.4f, nn, 3 * nn, n, n, tmpA);
        colpass_kernel<<<cg, cb, 0, stream>>>(yh1 + 1 * nn, yh1 + 2 * nn, 0.4f, 0.4f, 3 * nn, 3 * nn, n, n, tmpB);
        dim3 rg(n / 64, (2 * n) / 4, C);
        rowpass_kernel<<<rg, cb, 0, stream>>>(tmpA, tmpB, n, llbuf);
    }
    // ---- Level 3: n=512 -> 1024. details yh0 * 0.2; fp16 tmps, fused HWC output
    {
        int nn = 512 * 512;
        dim3 cg(2, 128, C);
        colpass4h_kernel<<<cg, cb, 0, stream>>>((const float4*)llbuf, (const float4*)(yh0 + 0 * nn),
                                                1.0f, 0.2f, nn / 4, 3 * nn / 4, tmpAh);
        colpass4h_kernel<<<cg, cb, 0, stream>>>((const float4*)(yh0 + 1 * nn), (const float4*)(yh0 + 2 * nn),
                                                0.2f, 0.2f, 3 * nn / 4, 3 * nn / 4, tmpBh);
        dim3 rg(8, 1024);
        rowpass16_hwc_kernel<<<rg, 256, 0, stream>>>(tmpAh, tmpBh, planeHWC);
    }
    // ---- Bilinear sampling from fp16 HWC plane
    sample_kernel<<<(npts * 4 + 255) / 256, 256, 0, stream>>>(pts, planeHWC, (float*)d_out, npts);
}

// Round 5
// 276.076 us; speedup vs baseline: 2.5040x; 1.0327x over previous
//
#include <hip/hip_runtime.h>
#include <hip/hip_bf16.h>
#include <hip/hip_fp16.h>

// coif4 decomposition low-pass filter (L=24), fp32
constexpr int L = 24;
__device__ __constant__ float DEC_LO[L] = {
    -1.7849850030882614e-06f, -3.2596802368833675e-06f, 3.1229875865345646e-05f,
    6.233903446100713e-05f, -0.00025997455248771324f, -0.0005890207562443383f,
    0.0012665619292989445f, 0.003751436157278457f, -0.00565828668661072f,
    -0.015211731527946259f, 0.025082261844864097f, 0.03933442712333749f,
    -0.09622044203398798f, -0.06662747426342504f, 0.4343860564914685f,
    0.782238930920499f, 0.41530840703043026f, -0.05607731331675481f,
    -0.08126669968087875f, 0.026682300156053072f, 0.016068943964776348f,
    -0.0073461663276420935f, -0.0016294920126017326f, 0.0008923136685823146f
};

// g0[m] = DEC_LO[23-m] (reconstruction low), g1[m] = (-1)^m DEC_LO[m] (reconstruction high)
__device__ __forceinline__ float g0f(int m) { return DEC_LO[23 - m]; }
__device__ __forceinline__ float g1f(int m) { return (m & 1) ? -DEC_LO[m] : DEC_LO[m]; }

// ---------------- L1/L2: merged col-pass (A and B in one dispatch, z selects) ----------------
// A: (lowA,highA) -> outA; B: (lowB,highB) -> outB. All fp32, (C,n,W) -> (C,2n,W).
__global__ void colpass2_kernel(const float* __restrict__ lowA, const float* __restrict__ highA,
                                float sLA, float sHA, int lACS, int hACS,
                                const float* __restrict__ lowB, const float* __restrict__ highB,
                                float sLB, float sHB, int lBCS, int hBCS,
                                int n, int W,
                                float* __restrict__ outA, float* __restrict__ outB)
{
    int x = blockIdx.x * 64 + threadIdx.x;
    int q = blockIdx.y * blockDim.y + threadIdx.y;
    int z = blockIdx.z;
    int c = z & 31;
    bool isB = z >= 32;                  // block-uniform
    const float* low  = isB ? lowB  : lowA;
    const float* high = isB ? highB : highA;
    float sLow  = isB ? sLB : sLA;
    float sHigh = isB ? sHB : sHA;
    int lowCS  = isB ? lBCS : lACS;
    int highCS = isB ? hBCS : hACS;
    float* out = isB ? outB : outA;

    int mask = n - 1;
    const float* lp = low + (size_t)c * lowCS + x;
    const float* hp = high + (size_t)c * highCS + x;
    float a0 = 0.f, a1 = 0.f;
#pragma unroll
    for (int s = 0; s <= 12; ++s) {
        int r = (q + 6 - s) & mask;
        float lv = sLow * lp[(size_t)r * W];
        float hv = sHigh * hp[(size_t)r * W];
        if (s >= 1)  a0 = fmaf(g0f(2 * s - 1), lv, fmaf(g1f(2 * s - 1), hv, a0));
        if (s <= 11) a1 = fmaf(g0f(2 * s), lv, fmaf(g1f(2 * s), hv, a1));
    }
    size_t ob = ((size_t)c * (2 * n) + 2 * q) * W + x;
    out[ob] = a0;
    out[ob + W] = a1;
}

__global__ void rowpass_kernel(const float* __restrict__ lo, const float* __restrict__ hi,
                               int n, float* __restrict__ out)
{
    int q = blockIdx.x * 64 + threadIdx.x;
    int y = blockIdx.y * blockDim.y + threadIdx.y;
    int c = blockIdx.z;
    int N = 2 * n, mask = n - 1;
    const float* lp = lo + ((size_t)c * N + y) * n;
    const float* hp = hi + ((size_t)c * N + y) * n;
    float a0 = 0.f, a1 = 0.f;
#pragma unroll
    for (int s = 0; s <= 12; ++s) {
        int r = (q + 6 - s) & mask;
        float lv = lp[r];
        float hv = hp[r];
        if (s >= 1)  a0 = fmaf(g0f(2 * s - 1), lv, fmaf(g1f(2 * s - 1), hv, a0));
        if (s <= 11) a1 = fmaf(g0f(2 * s), lv, fmaf(g1f(2 * s), hv, a1));
    }
    float2* op = (float2*)(out + ((size_t)c * N + y) * N + 2 * q);
    *op = make_float2(a0, a1);
}

// ---------------- Level-3 merged col-pass: float4 over x, fp16 out ----------------
// z<32: (loA,hiA,sLA,sHA)->outA ; z>=32: (loB,hiB,...)->outB. In fp32, out fp16 (32,1024,512).
__global__ void colpass4h2_kernel(const float4* __restrict__ loA, const float4* __restrict__ hiA,
                                  float sLA, float sHA, int lACS4, int hACS4,
                                  const float4* __restrict__ loB, const float4* __restrict__ hiB,
                                  float sLB, float sHB, int lBCS4, int hBCS4,
                                  __half* __restrict__ outA, __half* __restrict__ outB)
{
    const int mask = 511, W4 = 128;
    int x = blockIdx.x * 64 + threadIdx.x;   // float4 index, [0,128)
    int q = blockIdx.y * 4 + threadIdx.y;    // [0,512)
    int z = blockIdx.z;
    int c = z & 31;
    bool isB = z >= 32;
    const float4* lo = isB ? loB : loA;
    const float4* hi = isB ? hiB : hiA;
    float sLow  = isB ? sLB : sLA;
    float sHigh = isB ? sHB : sHA;
    int loCS4 = isB ? lBCS4 : lACS4;
    int hiCS4 = isB ? hBCS4 : hACS4;
    __half* out = isB ? outB : outA;

    const float4* lp = lo + (size_t)c * loCS4 + x;
    const float4* hp = hi + (size_t)c * hiCS4 + x;
    float4 a0 = make_float4(0.f, 0.f, 0.f, 0.f);
    float4 a1 = make_float4(0.f, 0.f, 0.f, 0.f);
#pragma unroll
    for (int s = 0; s <= 12; ++s) {
        int r = (q + 6 - s) & mask;
        float4 lv = lp[(size_t)r * W4];
        float4 hv = hp[(size_t)r * W4];
        if (s >= 1) {
            float gl = g0f(2 * s - 1) * sLow, gh = g1f(2 * s - 1) * sHigh;
            a0.x = fmaf(gl, lv.x, fmaf(gh, hv.x, a0.x));
            a0.y = fmaf(gl, lv.y, fmaf(gh, hv.y, a0.y));
            a0.z = fmaf(gl, lv.z, fmaf(gh, hv.z, a0.z));
            a0.w = fmaf(gl, lv.w, fmaf(gh, hv.w, a0.w));
        }
        if (s <= 11) {
            float gl = g0f(2 * s) * sLow, gh = g1f(2 * s) * sHigh;
            a1.x = fmaf(gl, lv.x, fmaf(gh, hv.x, a1.x));
            a1.y = fmaf(gl, lv.y, fmaf(gh, hv.y, a1.y));
            a1.z = fmaf(gl, lv.z, fmaf(gh, hv.z, a1.z));
            a1.w = fmaf(gl, lv.w, fmaf(gh, hv.w, a1.w));
        }
    }
    size_t ob = ((size_t)c * 1024 + 2 * q) * 512 + 4 * x;
    __half2 p0 = __floats2half2_rn(a0.x, a0.y), p1 = __floats2half2_rn(a0.z, a0.w);
    __half2 p2 = __floats2half2_rn(a1.x, a1.y), p3 = __floats2half2_rn(a1.z, a1.w);
    *(uint2*)&out[ob]       = make_uint2(*(unsigned int*)&p0, *(unsigned int*)&p1);
    *(uint2*)&out[ob + 512] = make_uint2(*(unsigned int*)&p2, *(unsigned int*)&p3);
}

// ---------------- Level-3 rowpass fused with HWC output (unchanged from R4) ----------------
__global__ void rowpass16_hwc_kernel(const __half* __restrict__ lo, const __half* __restrict__ hi,
                                     __half* __restrict__ out)
{
    const int n = 512, N = 1024, mask = 511;
    int y = blockIdx.y;
    int qb = blockIdx.x * 64;
    int t = threadIdx.x;
    int c = t >> 3;
    int tq = t & 7;
    int q0 = qb + tq * 8;

    const __half* lp = lo + ((size_t)c * N + y) * n;
    const __half* hp = hi + ((size_t)c * N + y) * n;

    float wlo[24], whi[24];
#pragma unroll
    for (int k = 0; k < 3; ++k) {
        int s0 = (q0 - 8 + 8 * k) & mask;
        float4 vl = *(const float4*)(lp + s0);
        float4 vh = *(const float4*)(hp + s0);
        const __half2* hl = (const __half2*)&vl;
        const __half2* hh = (const __half2*)&vh;
#pragma unroll
        for (int j = 0; j < 4; ++j) {
            float2 fl = __half22float2(hl[j]);
            float2 fh = __half22float2(hh[j]);
            wlo[k * 8 + 2 * j]     = fl.x;
            wlo[k * 8 + 2 * j + 1] = fl.y;
            whi[k * 8 + 2 * j]     = fh.x;
            whi[k * 8 + 2 * j + 1] = fh.y;
        }
    }

    __shared__ __half tile[128][34];

#pragma unroll
    for (int j = 0; j < 8; ++j) {
        float a0 = 0.f, a1 = 0.f;
#pragma unroll
        for (int s = 0; s <= 12; ++s) {
            int li = j + 14 - s;
            float lv = wlo[li];
            float hv = whi[li];
            if (s >= 1)  a0 = fmaf(g0f(2 * s - 1), lv, fmaf(g1f(2 * s - 1), hv, a0));
            if (s <= 11) a1 = fmaf(g0f(2 * s), lv, fmaf(g1f(2 * s), hv, a1));
        }
        int pl = 16 * tq + 2 * j;
        tile[pl][c]     = __float2half_rn(a0);
        tile[pl + 1][c] = __float2half_rn(a1);
    }
    __syncthreads();

    int p = t >> 1;
    int c0 = (t & 1) * 16;
    unsigned int w[8];
#pragma unroll
    for (int k = 0; k < 8; ++k) {
        unsigned int l16 = __half_as_ushort(tile[p][c0 + 2 * k]);
        unsigned int h16 = __half_as_ushort(tile[p][c0 + 2 * k + 1]);
        w[k] = l16 | (h16 << 16);
    }
    size_t ob = ((size_t)y * 1024 + 2 * qb + p) * 32 + c0;
    *(uint4*)&out[ob]     = make_uint4(w[0], w[1], w[2], w[3]);
    *(uint4*)(&out[ob + 8]) = make_uint4(w[4], w[5], w[6], w[7]);
}

// ---------------- Sampler: 2 threads/point, 16 channels each, 8 x 16B loads in flight ----------------
struct alignas(16) HV { __half2 h[4]; };

__global__ __launch_bounds__(256) void sample_kernel(const float* __restrict__ pts,
                                                     const __half* __restrict__ plane,
                                                     float* __restrict__ out, int npts)
{
    int tid = blockIdx.x * 256 + threadIdx.x;
    int p = tid >> 1;
    int cg = (tid & 1) * 16;        // 16 channels per thread
    float2 pt = *(const float2*)(pts + 2 * p);
    float xf = fminf(fmaxf((pt.x + 1.f) * 0.5f * 1023.f, 0.f), 1023.f);
    float yf = fminf(fmaxf((pt.y + 1.f) * 0.5f * 1023.f, 0.f), 1023.f);
    int x0 = (int)xf, y0 = (int)yf;
    int x1 = min(x0 + 1, 1023), y1 = min(y0 + 1, 1023);
    float wx = xf - (float)x0, wy = yf - (float)y0;
    size_t r0 = (size_t)y0 * 1024, r1 = (size_t)y1 * 1024;
    const __half* base = plane + cg;
    // Issue all 8 independent 16B loads before consuming.
    HV v00a = *(const HV*)(base + (r0 + x0) * 32);
    HV v00b = *(const HV*)(base + (r0 + x0) * 32 + 8);
    HV v01a = *(const HV*)(base + (r0 + x1) * 32);
    HV v01b = *(const HV*)(base + (r0 + x1) * 32 + 8);
    HV v10a = *(const HV*)(base + (r1 + x0) * 32);
    HV v10b = *(const HV*)(base + (r1 + x0) * 32 + 8);
    HV v11a = *(const HV*)(base + (r1 + x1) * 32);
    HV v11b = *(const HV*)(base + (r1 + x1) * 32 + 8);

    float o[16];
#pragma unroll
    for (int k = 0; k < 4; ++k) {
        float2 f00 = __half22float2(v00a.h[k]);
        float2 f01 = __half22float2(v01a.h[k]);
        float2 f10 = __half22float2(v10a.h[k]);
        float2 f11 = __half22float2(v11a.h[k]);
        o[2 * k]     = (f00.x * (1.f - wx) + f01.x * wx) * (1.f - wy)
                     + (f10.x * (1.f - wx) + f11.x * wx) * wy;
        o[2 * k + 1] = (f00.y * (1.f - wx) + f01.y * wx) * (1.f - wy)
                     + (f10.y * (1.f - wx) + f11.y * wx) * wy;
    }
#pragma unroll
    for (int k = 0; k < 4; ++k) {
        float2 f00 = __half22float2(v00b.h[k]);
        float2 f01 = __half22float2(v01b.h[k]);
        float2 f10 = __half22float2(v10b.h[k]);
        float2 f11 = __half22float2(v11b.h[k]);
        o[8 + 2 * k]     = (f00.x * (1.f - wx) + f01.x * wx) * (1.f - wy)
                         + (f10.x * (1.f - wx) + f11.x * wx) * wy;
        o[8 + 2 * k + 1] = (f00.y * (1.f - wx) + f01.y * wx) * (1.f - wy)
                         + (f10.y * (1.f - wx) + f11.y * wx) * wy;
    }
    float* ob = out + (size_t)p * 32 + cg;
    *(float4*)ob        = make_float4(o[0], o[1], o[2], o[3]);
    *(float4*)(ob + 4)  = make_float4(o[4], o[5], o[6], o[7]);
    *(float4*)(ob + 8)  = make_float4(o[8], o[9], o[10], o[11]);
    *(float4*)(ob + 12) = make_float4(o[12], o[13], o[14], o[15]);
}

extern "C" void kernel_launch(void* const* d_in, const int* in_sizes, int n_in,
                              void* d_out, int out_size, void* d_ws, size_t ws_size,
                              hipStream_t stream)
{
    const float* pts = (const float*)d_in[0];
    const float* yl  = (const float*)d_in[1];
    const float* yh0 = (const float*)d_in[2]; // (32,3,512,512), scale 0.2, level 3
    const float* yh1 = (const float*)d_in[3]; // (32,3,256,256), scale 0.4, level 2
    const float* yh2 = (const float*)d_in[4]; // (32,3,128,128), scale 0.6, level 1
    const int npts = in_sizes[0] / 2;

    // Workspace layout (bytes), total 167.8 MB:
    //   [0,          33554432)  llbuf    fp32 (up to C x 512 x 512)
    //   [33554432,   67108864)  tmpA     fp32 (L1/L2) / fp16 (L3: C x 1024 x 512)
    //   [67108864,  100663296)  tmpB     same
    //   [100663296, 167772160)  planeHWC fp16 (1024,1024,C)
    char* ws = (char*)d_ws;
    float*  llbuf    = (float*)ws;
    float*  tmpA     = (float*)(ws + 33554432);
    float*  tmpB     = (float*)(ws + 67108864);
    __half* tmpAh    = (__half*)(ws + 33554432);
    __half* tmpBh    = (__half*)(ws + 67108864);
    __half* planeHWC = (__half*)(ws + 100663296);

    dim3 cb(64, 4, 1);

    // ---- Level 1: n=128 -> 256. A: (yl, yh2-LH); B: (yh2-HL, yh2-HH)
    {
        int n = 128, nn = n * n;
        dim3 cg(n / 64, n / 4, 64);
        colpass2_kernel<<<cg, cb, 0, stream>>>(yl, yh2 + 0 * nn, 1.0f, 0.6f, nn, 3 * nn,
                                               yh2 + 1 * nn, yh2 + 2 * nn, 0.6f, 0.6f, 3 * nn, 3 * nn,
                                               n, n, tmpA, tmpB);
        dim3 rg(n / 64, (2 * n) / 4, 32);
        rowpass_kernel<<<rg, cb, 0, stream>>>(tmpA, tmpB, n, llbuf);
    }
    // ---- Level 2: n=256 -> 512
    {
        int n = 256, nn = n * n;
        dim3 cg(n / 64, n / 4, 64);
        colpass2_kernel<<<cg, cb, 0, stream>>>(llbuf, yh1 + 0 * nn, 1.0f, 0.4f, nn, 3 * nn,
                                               yh1 + 1 * nn, yh1 + 2 * nn, 0.4f, 0.4f, 3 * nn, 3 * nn,
                                               n, n, tmpA, tmpB);
        dim3 rg(n / 64, (2 * n) / 4, 32);
        rowpass_kernel<<<rg, cb, 0, stream>>>(tmpA, tmpB, n, llbuf);
    }
    // ---- Level 3: n=512 -> 1024, fp16 tmps, fused HWC output
    {
        int nn = 512 * 512;
        dim3 cg(2, 128, 64);
        colpass4h2_kernel<<<cg, cb, 0, stream>>>(
            (const float4*)llbuf, (const float4*)(yh0 + 0 * nn), 1.0f, 0.2f, nn / 4, 3 * nn / 4,
            (const float4*)(yh0 + 1 * nn), (const float4*)(yh0 + 2 * nn), 0.2f, 0.2f, 3 * nn / 4, 3 * nn / 4,
            tmpAh, tmpBh);
        dim3 rg(8, 1024);
        rowpass16_hwc_kernel<<<rg, 256, 0, stream>>>(tmpAh, tmpBh, planeHWC);
    }
    // ---- Bilinear sampling: 2 threads/point
    sample_kernel<<<(npts * 2) / 256, 256, 0, stream>>>(pts, planeHWC, (float*)d_out, npts);
}

// Round 6
// 254.319 us; speedup vs baseline: 2.7183x; 1.0856x over previous
//
#include <hip/hip_runtime.h>
#include <hip/hip_bf16.h>
#include <hip/hip_fp16.h>

// coif4 decomposition low-pass filter (L=24), fp32
constexpr int L = 24;
__device__ __constant__ float DEC_LO[L] = {
    -1.7849850030882614e-06f, -3.2596802368833675e-06f, 3.1229875865345646e-05f,
    6.233903446100713e-05f, -0.00025997455248771324f, -0.0005890207562443383f,
    0.0012665619292989445f, 0.003751436157278457f, -0.00565828668661072f,
    -0.015211731527946259f, 0.025082261844864097f, 0.03933442712333749f,
    -0.09622044203398798f, -0.06662747426342504f, 0.4343860564914685f,
    0.782238930920499f, 0.41530840703043026f, -0.05607731331675481f,
    -0.08126669968087875f, 0.026682300156053072f, 0.016068943964776348f,
    -0.0073461663276420935f, -0.0016294920126017326f, 0.0008923136685823146f
};

// g0[m] = DEC_LO[23-m] (reconstruction low), g1[m] = (-1)^m DEC_LO[m] (reconstruction high)
__device__ __forceinline__ float g0f(int m) { return DEC_LO[23 - m]; }
__device__ __forceinline__ float g1f(int m) { return (m & 1) ? -DEC_LO[m] : DEC_LO[m]; }

// ---------------- L1/L2: merged col-pass (A and B in one dispatch, z selects) ----------------
__global__ void colpass2_kernel(const float* __restrict__ lowA, const float* __restrict__ highA,
                                float sLA, float sHA, int lACS, int hACS,
                                const float* __restrict__ lowB, const float* __restrict__ highB,
                                float sLB, float sHB, int lBCS, int hBCS,
                                int n, int W,
                                float* __restrict__ outA, float* __restrict__ outB)
{
    int x = blockIdx.x * 64 + threadIdx.x;
    int q = blockIdx.y * blockDim.y + threadIdx.y;
    int z = blockIdx.z;
    int c = z & 31;
    bool isB = z >= 32;                  // block-uniform
    const float* low  = isB ? lowB  : lowA;
    const float* high = isB ? highB : highA;
    float sLow  = isB ? sLB : sLA;
    float sHigh = isB ? sHB : sHA;
    int lowCS  = isB ? lBCS : lACS;
    int highCS = isB ? hBCS : hACS;
    float* out = isB ? outB : outA;

    int mask = n - 1;
    const float* lp = low + (size_t)c * lowCS + x;
    const float* hp = high + (size_t)c * highCS + x;
    float a0 = 0.f, a1 = 0.f;
#pragma unroll
    for (int s = 0; s <= 12; ++s) {
        int r = (q + 6 - s) & mask;
        float lv = sLow * lp[(size_t)r * W];
        float hv = sHigh * hp[(size_t)r * W];
        if (s >= 1)  a0 = fmaf(g0f(2 * s - 1), lv, fmaf(g1f(2 * s - 1), hv, a0));
        if (s <= 11) a1 = fmaf(g0f(2 * s), lv, fmaf(g1f(2 * s), hv, a1));
    }
    size_t ob = ((size_t)c * (2 * n) + 2 * q) * W + x;
    out[ob] = a0;
    out[ob + W] = a1;
}

__global__ void rowpass_kernel(const float* __restrict__ lo, const float* __restrict__ hi,
                               int n, float* __restrict__ out)
{
    int q = blockIdx.x * 64 + threadIdx.x;
    int y = blockIdx.y * blockDim.y + threadIdx.y;
    int c = blockIdx.z;
    int N = 2 * n, mask = n - 1;
    const float* lp = lo + ((size_t)c * N + y) * n;
    const float* hp = hi + ((size_t)c * N + y) * n;
    float a0 = 0.f, a1 = 0.f;
#pragma unroll
    for (int s = 0; s <= 12; ++s) {
        int r = (q + 6 - s) & mask;
        float lv = lp[r];
        float hv = hp[r];
        if (s >= 1)  a0 = fmaf(g0f(2 * s - 1), lv, fmaf(g1f(2 * s - 1), hv, a0));
        if (s <= 11) a1 = fmaf(g0f(2 * s), lv, fmaf(g1f(2 * s), hv, a1));
    }
    float2* op = (float2*)(out + ((size_t)c * N + y) * N + 2 * q);
    *op = make_float2(a0, a1);
}

// ---------------- Level-3 merged col-pass: register-blocked 4 q/thread ----------------
// Streams the 16-row union window once; each loaded row FMAs into all live accumulators.
// z<32: (loA,hiA)->outA ; z>=32: (loB,hiB)->outB. In fp32, out fp16 (32,1024,512).
__global__ void colpass4h2_kernel(const float4* __restrict__ loA, const float4* __restrict__ hiA,
                                  float sLA, float sHA, int lACS4, int hACS4,
                                  const float4* __restrict__ loB, const float4* __restrict__ hiB,
                                  float sLB, float sHB, int lBCS4, int hBCS4,
                                  __half* __restrict__ outA, __half* __restrict__ outB)
{
    const int mask = 511, W4 = 128;
    int x = blockIdx.x * 64 + threadIdx.x;              // float4 index, [0,128)
    int q0 = (blockIdx.y * 4 + threadIdx.y) * 4;        // 4 q-pairs per thread
    int z = blockIdx.z;
    int c = z & 31;
    bool isB = z >= 32;
    const float4* lo = isB ? loB : loA;
    const float4* hi = isB ? hiB : hiA;
    float sLow  = isB ? sLB : sLA;
    float sHigh = isB ? sHB : sHA;
    int loCS4 = isB ? lBCS4 : lACS4;
    int hiCS4 = isB ? hBCS4 : hACS4;
    __half* out = isB ? outB : outA;

    const float4* lp = lo + (size_t)c * loCS4 + x;
    const float4* hp = hi + (size_t)c * hiCS4 + x;

    float4 a0[4], a1[4];
#pragma unroll
    for (int j = 0; j < 4; ++j) {
        a0[j] = make_float4(0.f, 0.f, 0.f, 0.f);
        a1[j] = make_float4(0.f, 0.f, 0.f, 0.f);
    }

    // Union window of rows for q0..q0+3: r = q0-6 .. q0+9 (16 rows).
    // Tap index for output j at window slot ro: s = j + 12 - ro (compile-time).
#pragma unroll
    for (int ro = 0; ro < 16; ++ro) {
        int r = (q0 - 6 + ro) & mask;
        float4 lv = lp[(size_t)r * W4];
        float4 hv = hp[(size_t)r * W4];
        lv.x *= sLow;  lv.y *= sLow;  lv.z *= sLow;  lv.w *= sLow;
        hv.x *= sHigh; hv.y *= sHigh; hv.z *= sHigh; hv.w *= sHigh;
#pragma unroll
        for (int j = 0; j < 4; ++j) {
            int s = j + 12 - ro;
            if (s >= 1 && s <= 12) {
                float gl = g0f(2 * s - 1), gh = g1f(2 * s - 1);
                a0[j].x = fmaf(gl, lv.x, fmaf(gh, hv.x, a0[j].x));
                a0[j].y = fmaf(gl, lv.y, fmaf(gh, hv.y, a0[j].y));
                a0[j].z = fmaf(gl, lv.z, fmaf(gh, hv.z, a0[j].z));
                a0[j].w = fmaf(gl, lv.w, fmaf(gh, hv.w, a0[j].w));
            }
            if (s >= 0 && s <= 11) {
                float gl = g0f(2 * s), gh = g1f(2 * s);
                a1[j].x = fmaf(gl, lv.x, fmaf(gh, hv.x, a1[j].x));
                a1[j].y = fmaf(gl, lv.y, fmaf(gh, hv.y, a1[j].y));
                a1[j].z = fmaf(gl, lv.z, fmaf(gh, hv.z, a1[j].z));
                a1[j].w = fmaf(gl, lv.w, fmaf(gh, hv.w, a1[j].w));
            }
        }
    }

#pragma unroll
    for (int j = 0; j < 4; ++j) {
        size_t ob = ((size_t)c * 1024 + 2 * (q0 + j)) * 512 + 4 * x;
        __half2 p0 = __floats2half2_rn(a0[j].x, a0[j].y), p1 = __floats2half2_rn(a0[j].z, a0[j].w);
        __half2 p2 = __floats2half2_rn(a1[j].x, a1[j].y), p3 = __floats2half2_rn(a1[j].z, a1[j].w);
        *(uint2*)&out[ob]       = make_uint2(*(unsigned int*)&p0, *(unsigned int*)&p1);
        *(uint2*)&out[ob + 512] = make_uint2(*(unsigned int*)&p2, *(unsigned int*)&p3);
    }
}

// ---------------- Level-3 rowpass fused with HWC output (unchanged) ----------------
__global__ void rowpass16_hwc_kernel(const __half* __restrict__ lo, const __half* __restrict__ hi,
                                     __half* __restrict__ out)
{
    const int n = 512, N = 1024, mask = 511;
    int y = blockIdx.y;
    int qb = blockIdx.x * 64;
    int t = threadIdx.x;
    int c = t >> 3;
    int tq = t & 7;
    int q0 = qb + tq * 8;

    const __half* lp = lo + ((size_t)c * N + y) * n;
    const __half* hp = hi + ((size_t)c * N + y) * n;

    float wlo[24], whi[24];
#pragma unroll
    for (int k = 0; k < 3; ++k) {
        int s0 = (q0 - 8 + 8 * k) & mask;
        float4 vl = *(const float4*)(lp + s0);
        float4 vh = *(const float4*)(hp + s0);
        const __half2* hl = (const __half2*)&vl;
        const __half2* hh = (const __half2*)&vh;
#pragma unroll
        for (int j = 0; j < 4; ++j) {
            float2 fl = __half22float2(hl[j]);
            float2 fh = __half22float2(hh[j]);
            wlo[k * 8 + 2 * j]     = fl.x;
            wlo[k * 8 + 2 * j + 1] = fl.y;
            whi[k * 8 + 2 * j]     = fh.x;
            whi[k * 8 + 2 * j + 1] = fh.y;
        }
    }

    __shared__ __half tile[128][34];

#pragma unroll
    for (int j = 0; j < 8; ++j) {
        float a0 = 0.f, a1 = 0.f;
#pragma unroll
        for (int s = 0; s <= 12; ++s) {
            int li = j + 14 - s;
            float lv = wlo[li];
            float hv = whi[li];
            if (s >= 1)  a0 = fmaf(g0f(2 * s - 1), lv, fmaf(g1f(2 * s - 1), hv, a0));
            if (s <= 11) a1 = fmaf(g0f(2 * s), lv, fmaf(g1f(2 * s), hv, a1));
        }
        int pl = 16 * tq + 2 * j;
        tile[pl][c]     = __float2half_rn(a0);
        tile[pl + 1][c] = __float2half_rn(a1);
    }
    __syncthreads();

    int p = t >> 1;
    int c0 = (t & 1) * 16;
    unsigned int w[8];
#pragma unroll
    for (int k = 0; k < 8; ++k) {
        unsigned int l16 = __half_as_ushort(tile[p][c0 + 2 * k]);
        unsigned int h16 = __half_as_ushort(tile[p][c0 + 2 * k + 1]);
        w[k] = l16 | (h16 << 16);
    }
    size_t ob = ((size_t)y * 1024 + 2 * qb + p) * 32 + c0;
    *(uint4*)&out[ob]       = make_uint4(w[0], w[1], w[2], w[3]);
    *(uint4*)(&out[ob + 8]) = make_uint4(w[4], w[5], w[6], w[7]);
}

// ---------------- Sampler: 2 threads/point, 16 channels each (unchanged) ----------------
struct alignas(16) HV { __half2 h[4]; };

__global__ __launch_bounds__(256) void sample_kernel(const float* __restrict__ pts,
                                                     const __half* __restrict__ plane,
                                                     float* __restrict__ out, int npts)
{
    int tid = blockIdx.x * 256 + threadIdx.x;
    int p = tid >> 1;
    int cg = (tid & 1) * 16;
    float2 pt = *(const float2*)(pts + 2 * p);
    float xf = fminf(fmaxf((pt.x + 1.f) * 0.5f * 1023.f, 0.f), 1023.f);
    float yf = fminf(fmaxf((pt.y + 1.f) * 0.5f * 1023.f, 0.f), 1023.f);
    int x0 = (int)xf, y0 = (int)yf;
    int x1 = min(x0 + 1, 1023), y1 = min(y0 + 1, 1023);
    float wx = xf - (float)x0, wy = yf - (float)y0;
    size_t r0 = (size_t)y0 * 1024, r1 = (size_t)y1 * 1024;
    const __half* base = plane + cg;
    HV v00a = *(const HV*)(base + (r0 + x0) * 32);
    HV v00b = *(const HV*)(base + (r0 + x0) * 32 + 8);
    HV v01a = *(const HV*)(base + (r0 + x1) * 32);
    HV v01b = *(const HV*)(base + (r0 + x1) * 32 + 8);
    HV v10a = *(const HV*)(base + (r1 + x0) * 32);
    HV v10b = *(const HV*)(base + (r1 + x0) * 32 + 8);
    HV v11a = *(const HV*)(base + (r1 + x1) * 32);
    HV v11b = *(const HV*)(base + (r1 + x1) * 32 + 8);

    float o[16];
#pragma unroll
    for (int k = 0; k < 4; ++k) {
        float2 f00 = __half22float2(v00a.h[k]);
        float2 f01 = __half22float2(v01a.h[k]);
        float2 f10 = __half22float2(v10a.h[k]);
        float2 f11 = __half22float2(v11a.h[k]);
        o[2 * k]     = (f00.x * (1.f - wx) + f01.x * wx) * (1.f - wy)
                     + (f10.x * (1.f - wx) + f11.x * wx) * wy;
        o[2 * k + 1] = (f00.y * (1.f - wx) + f01.y * wx) * (1.f - wy)
                     + (f10.y * (1.f - wx) + f11.y * wx) * wy;
    }
#pragma unroll
    for (int k = 0; k < 4; ++k) {
        float2 f00 = __half22float2(v00b.h[k]);
        float2 f01 = __half22float2(v01b.h[k]);
        float2 f10 = __half22float2(v10b.h[k]);
        float2 f11 = __half22float2(v11b.h[k]);
        o[8 + 2 * k]     = (f00.x * (1.f - wx) + f01.x * wx) * (1.f - wy)
                         + (f10.x * (1.f - wx) + f11.x * wx) * wy;
        o[8 + 2 * k + 1] = (f00.y * (1.f - wx) + f01.y * wx) * (1.f - wy)
                         + (f10.y * (1.f - wx) + f11.y * wx) * wy;
    }
    float* ob = out + (size_t)p * 32 + cg;
    *(float4*)ob        = make_float4(o[0], o[1], o[2], o[3]);
    *(float4*)(ob + 4)  = make_float4(o[4], o[5], o[6], o[7]);
    *(float4*)(ob + 8)  = make_float4(o[8], o[9], o[10], o[11]);
    *(float4*)(ob + 12) = make_float4(o[12], o[13], o[14], o[15]);
}

extern "C" void kernel_launch(void* const* d_in, const int* in_sizes, int n_in,
                              void* d_out, int out_size, void* d_ws, size_t ws_size,
                              hipStream_t stream)
{
    const float* pts = (const float*)d_in[0];
    const float* yl  = (const float*)d_in[1];
    const float* yh0 = (const float*)d_in[2]; // (32,3,512,512), scale 0.2, level 3
    const float* yh1 = (const float*)d_in[3]; // (32,3,256,256), scale 0.4, level 2
    const float* yh2 = (const float*)d_in[4]; // (32,3,128,128), scale 0.6, level 1
    const int npts = in_sizes[0] / 2;

    // Workspace layout (bytes), total 167.8 MB:
    //   [0,          33554432)  llbuf    fp32 (up to C x 512 x 512)
    //   [33554432,   67108864)  tmpA     fp32 (L1/L2) / fp16 (L3: C x 1024 x 512)
    //   [67108864,  100663296)  tmpB     same
    //   [100663296, 167772160)  planeHWC fp16 (1024,1024,C)
    char* ws = (char*)d_ws;
    float*  llbuf    = (float*)ws;
    float*  tmpA     = (float*)(ws + 33554432);
    float*  tmpB     = (float*)(ws + 67108864);
    __half* tmpAh    = (__half*)(ws + 33554432);
    __half* tmpBh    = (__half*)(ws + 67108864);
    __half* planeHWC = (__half*)(ws + 100663296);

    dim3 cb(64, 4, 1);

    // ---- Level 1: n=128 -> 256. A: (yl, yh2-LH); B: (yh2-HL, yh2-HH)
    {
        int n = 128, nn = n * n;
        dim3 cg(n / 64, n / 4, 64);
        colpass2_kernel<<<cg, cb, 0, stream>>>(yl, yh2 + 0 * nn, 1.0f, 0.6f, nn, 3 * nn,
                                               yh2 + 1 * nn, yh2 + 2 * nn, 0.6f, 0.6f, 3 * nn, 3 * nn,
                                               n, n, tmpA, tmpB);
        dim3 rg(n / 64, (2 * n) / 4, 32);
        rowpass_kernel<<<rg, cb, 0, stream>>>(tmpA, tmpB, n, llbuf);
    }
    // ---- Level 2: n=256 -> 512
    {
        int n = 256, nn = n * n;
        dim3 cg(n / 64, n / 4, 64);
        colpass2_kernel<<<cg, cb, 0, stream>>>(llbuf, yh1 + 0 * nn, 1.0f, 0.4f, nn, 3 * nn,
                                               yh1 + 1 * nn, yh1 + 2 * nn, 0.4f, 0.4f, 3 * nn, 3 * nn,
                                               n, n, tmpA, tmpB);
        dim3 rg(n / 64, (2 * n) / 4, 32);
        rowpass_kernel<<<rg, cb, 0, stream>>>(tmpA, tmpB, n, llbuf);
    }
    // ---- Level 3: n=512 -> 1024, register-blocked colpass, fp16 tmps, fused HWC rowpass
    {
        int nn = 512 * 512;
        dim3 cg(2, 32, 64);   // x-halves, 512q/(4thr*4q), A/B x channels
        colpass4h2_kernel<<<cg, cb, 0, stream>>>(
            (const float4*)llbuf, (const float4*)(yh0 + 0 * nn), 1.0f, 0.2f, nn / 4, 3 * nn / 4,
            (const float4*)(yh0 + 1 * nn), (const float4*)(yh0 + 2 * nn), 0.2f, 0.2f, 3 * nn / 4, 3 * nn / 4,
            tmpAh, tmpBh);
        dim3 rg(8, 1024);
        rowpass16_hwc_kernel<<<rg, 256, 0, stream>>>(tmpAh, tmpBh, planeHWC);
    }
    // ---- Bilinear sampling: 2 threads/point
    sample_kernel<<<(npts * 2) / 256, 256, 0, stream>>>(pts, planeHWC, (float*)d_out, npts);
}